// Round 13
// baseline (129.839 us; speedup 1.0000x reference)
//
#include <hip/hip_runtime.h>
#include <math.h>

#define NN 50000
#define NE 800000
#define NBUCK 98            // bucket = dst >> 9 (512 nodes/bucket)
#define BSH 9
#define CAP 16384           // per-bucket capacity (entries)
#define CHUNK 4096          // edges per bscatter chunk
#define NCH ((NE + CHUNK - 1) / CHUNK)   // 196
#define K1B 782             // k1 blocks in merged kernel
#define EPT2 8              // edges per thread in merged bscatter (CHUNK/512)
#define GSZ 16              // gathers per node per round

typedef float4 f4;
typedef float2 f2;
typedef unsigned short u16;
typedef unsigned int u32;

__device__ __forceinline__ float sigf(float x) {
    return __builtin_amdgcn_rcpf(1.0f + __expf(-x));
}

__device__ __forceinline__ u16 f32_to_bf16_rne(float f) {
    unsigned u = __float_as_uint(f);
    u += 0x7FFFu + ((u >> 16) & 1u);
    return (u16)(u >> 16);
}

// ---------------- Merged K1 + bscatter (independent work, one launch) -------
// Blocks [0,K1B): C = sig(z@Wc^T+bc); P = z@W1^T+bn; Qh = bf16(z@W2^T)
// Blocks [K1B,K1B+NCH): scatter packed edge entries into per-bucket regions.
#define K1_WFLOATS (3 * 32 * 64 * 2)           // 12288 floats = 48KB
__global__ __launch_bounds__(512, 4) void k1_sc(
    const float* __restrict__ z,
    const float* __restrict__ Wc, const float* __restrict__ bc,
    const float* __restrict__ Wn, const float* __restrict__ bn,
    float* __restrict__ P, u16* __restrict__ Qh, float* __restrict__ C,
    const int* __restrict__ esrc, const int* __restrict__ edst,
    int* __restrict__ gcur, u32* __restrict__ ebuf)
{
    const int tid = threadIdx.x;
    if (blockIdx.x < K1B) {
        __shared__ float sh[K1_WFLOATS + 8 * 256];  // 48KB weights + 8KB tiles
        f2* w2 = (f2*)sh;
        for (int j = tid; j < 3 * 32 * 64; j += 512) {
            const int m = j >> 11, r = j & 2047;
            const int k2 = r >> 6, h = r & 63;
            const float* s = (m == 0) ? (Wc + h * 64 + 2 * k2)
                                      : (Wn + h * 128 + (m - 1) * 64 + 2 * k2);
            w2[(m * 32 + k2) * 64 + h] = *(const f2*)s;
        }
        __syncthreads();

        const int lane = tid & 63;
        const int wid  = tid >> 6;
        f4* tile = (f4*)(sh + K1_WFLOATS) + wid * 64;
        const f2* wl0 = w2;
        const f2* wl1 = w2 + 32 * 64;
        const f2* wl2 = w2 + 2 * 32 * 64;
        const float bcur = bc[lane], bnbr = bn[lane];

        const int gw = blockIdx.x * 8 + wid;
        const int nw = K1B * 8;
        for (int chunk = gw; chunk < NN / 4; chunk += nw) {
            const int n0 = chunk * 4;
            tile[lane] = *(const f4*)(z + n0 * 64 + lane * 4);
            float a0[4], a1[4], a2[4];
            #pragma unroll
            for (int ni = 0; ni < 4; ++ni) { a0[ni] = 0.f; a1[ni] = 0.f; a2[ni] = 0.f; }
            #pragma unroll 2
            for (int k4 = 0; k4 < 16; ++k4) {
                const f2 w0a = wl0[(2 * k4) * 64 + lane], w0b = wl0[(2 * k4 + 1) * 64 + lane];
                const f2 w1a = wl1[(2 * k4) * 64 + lane], w1b = wl1[(2 * k4 + 1) * 64 + lane];
                const f2 w2a = wl2[(2 * k4) * 64 + lane], w2b = wl2[(2 * k4 + 1) * 64 + lane];
                #pragma unroll
                for (int ni = 0; ni < 4; ++ni) {
                    const f4 zz = tile[ni * 16 + k4];  // uniform addr -> LDS broadcast
                    a0[ni] = fmaf(w0b.y, zz.w, fmaf(w0b.x, zz.z, fmaf(w0a.y, zz.y, fmaf(w0a.x, zz.x, a0[ni]))));
                    a1[ni] = fmaf(w1b.y, zz.w, fmaf(w1b.x, zz.z, fmaf(w1a.y, zz.y, fmaf(w1a.x, zz.x, a1[ni]))));
                    a2[ni] = fmaf(w2b.y, zz.w, fmaf(w2b.x, zz.z, fmaf(w2a.y, zz.y, fmaf(w2a.x, zz.x, a2[ni]))));
                }
            }
            #pragma unroll
            for (int ni = 0; ni < 4; ++ni) {
                const int n = n0 + ni;
                C[n * 64 + lane]  = sigf(a0[ni] + bcur);
                P[n * 64 + lane]  = a1[ni] + bnbr;
                Qh[n * 64 + lane] = f32_to_bf16_rne(a2[ni]);
            }
        }
    } else {
        __shared__ int cnt[NBUCK];
        __shared__ int gbase[NBUCK];
        __shared__ int lcur[NBUCK];
        for (int i = tid; i < NBUCK; i += 512) cnt[i] = 0;
        __syncthreads();

        const int base = (blockIdx.x - K1B) * CHUNK;
        u32 ent[EPT2];
        int nb[EPT2];
        #pragma unroll
        for (int t = 0; t < EPT2; ++t) {
            const int e = base + t * 512 + tid;
            if (e < NE) {
                const int d = edst[e], s = esrc[e];
                const int b = d >> BSH;
                ent[t] = ((u32)(d & 511) << 16) | (u32)s;
                nb[t] = b;
                atomicAdd(&cnt[b], 1);
            } else {
                nb[t] = -1;
            }
        }
        __syncthreads();
        for (int i = tid; i < NBUCK; i += 512) {
            gbase[i] = cnt[i] ? atomicAdd(&gcur[i], cnt[i]) : 0;
            lcur[i] = 0;
        }
        __syncthreads();
        #pragma unroll
        for (int t = 0; t < EPT2; ++t) {
            if (nb[t] >= 0) {
                const int li = atomicAdd(&lcur[nb[t]], 1);
                ebuf[nb[t] * CAP + gbase[nb[t]] + li] = ent[t];
            }
        }
    }
}

// One block per bucket. Node segments rounded to 8 entries (16B aligned),
// pads zero-filled (gather node 0, contribution predicated off).
__global__ __launch_bounds__(256) void k_bsort(const int* __restrict__ gcur,
                                               const u32* __restrict__ ebuf,
                                               u32* __restrict__ bd,
                                               u16* __restrict__ ss)
{
    __shared__ int hist[512];
    __shared__ int lcur[512];
    __shared__ int ps[256];
    __shared__ int tot;
    const int b = blockIdx.x;
    const int ecnt = gcur[b];
    const int e0 = b * CAP;
    const int n0 = b << BSH;
    const int t = threadIdx.x;

    hist[t] = 0; hist[t + 256] = 0;
    __syncthreads();
    for (int j = t; j < ecnt; j += 256)
        atomicAdd(&hist[(ebuf[e0 + j] >> 16) & 511], 1);
    __syncthreads();
    const int a0 = hist[2 * t], a1 = hist[2 * t + 1];
    const int r0 = (a0 + 7) & ~7, r1 = (a1 + 7) & ~7;
    ps[t] = r0 + r1;
    __syncthreads();
    for (int o = 1; o < 256; o <<= 1) {
        int v = 0;
        if (t >= o) v = ps[t - o];
        __syncthreads();
        if (t >= o) ps[t] += v;
        __syncthreads();
    }
    const int excl = (t > 0) ? ps[t - 1] : 0;
    lcur[2 * t] = excl;
    lcur[2 * t + 1] = excl + r0;
    const int nA = n0 + 2 * t, nB = n0 + 2 * t + 1;
    if (nA < NN) bd[nA] = ((u32)(e0 + excl) << 8) | (u32)a0;
    if (nB < NN) bd[nB] = ((u32)(e0 + excl + r0) << 8) | (u32)a1;
    if (t == 255) tot = ps[255];
    __syncthreads();
    const int zw = (tot + 16) >> 1;
    u32* ssw = (u32*)(ss + e0);
    for (int j = t; j < zw; j += 256) ssw[j] = 0;
    __syncthreads();
    for (int j = t; j < ecnt; j += 256) {
        const u32 ent = ebuf[e0 + j];
        const int p = atomicAdd(&lcur[(ent >> 16) & 511], 1);
        ss[e0 + p] = (u16)(ent & 0xFFFFu);
    }
}

// ---------------- K2: pipelined 16-deep gather rounds -----------------------
// All loop VMEM is inline-asm so vmcnt accounting is wholly ours (rule #18
// fences after each wait). Round r: issue 16 gathers -> issue round r+1's
// 2 idx dwordx4 -> vmcnt(2) [gathers done, idx flying] -> sigmoids ->
// vmcnt(0) -> addrs for r+1. Hides idx-fetch latency under compute.
__global__ __launch_bounds__(256) void k2_agg(
    const u32* __restrict__ bd, const u16* __restrict__ ss,
    const float* __restrict__ P, const u16* __restrict__ Qh,
    float* __restrict__ NB)
{
    const int lane = threadIdx.x & 63;
    const int n = blockIdx.x * 4 + (threadIdx.x >> 6);
    if (n >= NN) return;
    const u32 w = bd[n];
    const int beg = __builtin_amdgcn_readfirstlane((int)(w >> 8));
    const int dg  = __builtin_amdgcn_readfirstlane((int)(w & 255u));
    const u16* qbl = Qh + lane;
    float acc = 0.f;

    if (dg > 0) {
        uint4 ivA0, ivA1, ivB0, ivB1;
        const u16* ip0 = ss + beg;
        asm volatile("global_load_dwordx4 %0, %1, off" : "=v"(ivA0) : "v"(ip0));
        asm volatile("global_load_dwordx4 %0, %1, off offset:16" : "=v"(ivA1) : "v"(ip0));
        float p;
        const float* pp = P + n * 64 + lane;
        asm volatile("global_load_dword %0, %1, off" : "=v"(p) : "v"(pp));
        asm volatile("s_waitcnt vmcnt(0)" ::: "memory");
        __builtin_amdgcn_sched_barrier(0);

        int jb = 0;
        while (true) {
            const u32 wv[8] = {ivA0.x, ivA0.y, ivA0.z, ivA0.w,
                               ivA1.x, ivA1.y, ivA1.z, ivA1.w};
            u32 q[GSZ];
            #pragma unroll
            for (int t8 = 0; t8 < 8; ++t8) {
                const u16* aL = qbl + ((wv[t8] & 0xFFFFu) << 6);
                const u16* aH = qbl + ((wv[t8] >> 16) << 6);
                asm volatile("global_load_ushort %0, %1, off" : "=v"(q[2 * t8])     : "v"(aL));
                asm volatile("global_load_ushort %0, %1, off" : "=v"(q[2 * t8 + 1]) : "v"(aH));
            }
            const int next = jb + GSZ;
            const bool more = next < dg;
            if (more) {
                const u16* ip2 = ss + beg + next;
                asm volatile("global_load_dwordx4 %0, %1, off" : "=v"(ivB0) : "v"(ip2));
                asm volatile("global_load_dwordx4 %0, %1, off offset:16" : "=v"(ivB1) : "v"(ip2));
                asm volatile("s_waitcnt vmcnt(2)" ::: "memory");
            } else {
                asm volatile("s_waitcnt vmcnt(0)" ::: "memory");
            }
            __builtin_amdgcn_sched_barrier(0);
            #pragma unroll
            for (int t = 0; t < GSZ; ++t) {
                const float m = sigf(p + __uint_as_float(q[t] << 16));
                acc += (jb + t < dg) ? m : 0.f;
            }
            if (!more) break;
            asm volatile("s_waitcnt vmcnt(0)" ::: "memory");
            __builtin_amdgcn_sched_barrier(0);
            ivA0 = ivB0; ivA1 = ivB1;
            jb = next;
        }
    }
    NB[n * 64 + lane] = acc;
}

// ---------------- K3: out = tanh([C|NB] @ Wo^T + bo) -----------------------
#define K3_WFLOATS (64 * 64 * 2)               // 8192 floats = 32KB
__global__ __launch_bounds__(512, 4) void k3_out(
    const float* __restrict__ C, const float* __restrict__ NB,
    const float* __restrict__ Wo, const float* __restrict__ bo,
    float* __restrict__ out)
{
    __shared__ float sh[K3_WFLOATS + 8 * 512];
    const int tid = threadIdx.x;
    f2* w2 = (f2*)sh;
    for (int j = tid; j < 64 * 64; j += 512) {
        const int k2 = j >> 6, d = j & 63;
        w2[k2 * 64 + d] = *(const f2*)(Wo + d * 128 + 2 * k2);
    }
    __syncthreads();

    const int lane = tid & 63;
    const int wid  = tid >> 6;
    f4* tile = (f4*)(sh + K3_WFLOATS) + wid * 128;
    const float bout = bo[lane];

    const int gw = blockIdx.x * 8 + wid;
    const int nw = gridDim.x * 8;
    for (int chunk = gw; chunk < NN / 4; chunk += nw) {
        const int n0 = chunk * 4;
        #pragma unroll
        for (int tt = 0; tt < 2; ++tt) {
            const int j = lane + tt * 64;
            const int ni = j >> 5, q = j & 31;
            const float* src = (q < 16) ? (C + (n0 + ni) * 64 + q * 4)
                                        : (NB + (n0 + ni) * 64 + (q - 16) * 4);
            tile[ni * 32 + q] = *(const f4*)src;
        }
        float acc[4];
        #pragma unroll
        for (int ni = 0; ni < 4; ++ni) acc[ni] = 0.f;
        #pragma unroll 2
        for (int k4 = 0; k4 < 32; ++k4) {
            const f2 wa = w2[(2 * k4) * 64 + lane];
            const f2 wb = w2[(2 * k4 + 1) * 64 + lane];
            #pragma unroll
            for (int ni = 0; ni < 4; ++ni) {
                const f4 hv = tile[ni * 32 + k4];
                acc[ni] = fmaf(wb.y, hv.w, fmaf(wb.x, hv.z, fmaf(wa.y, hv.y, fmaf(wa.x, hv.x, acc[ni]))));
            }
        }
        #pragma unroll
        for (int ni = 0; ni < 4; ++ni)
            out[(n0 + ni) * 64 + lane] = tanhf(acc[ni] + bout);
    }
}

extern "C" void kernel_launch(void* const* d_in, const int* in_sizes, int n_in,
                              void* d_out, int out_size, void* d_ws, size_t ws_size,
                              hipStream_t stream) {
    const float* z  = (const float*)d_in[0];
    const int* esrc = (const int*)d_in[1];
    const int* edst = (const int*)d_in[2];
    const float* Wc = (const float*)d_in[3];
    const float* bc = (const float*)d_in[4];
    const float* Wn = (const float*)d_in[5];
    const float* bn = (const float*)d_in[6];
    const float* Wo = (const float*)d_in[7];
    const float* bo = (const float*)d_in[8];
    float* out = (float*)d_out;

    float* P   = (float*)d_ws;                   // [NN*64] f32
    float* C   = P + (size_t)NN * 64;            // [NN*64] f32
    float* NB  = C + (size_t)NN * 64;            // [NN*64] f32
    u16* Qh    = (u16*)(NB + (size_t)NN * 64);   // [NN*64] bf16
    u32* bd    = (u32*)(Qh + (size_t)NN * 64);   // [NN] packed (beg<<8)|deg
    int* gcur  = (int*)(bd + NN + 64);           // [128]
    u32* ebuf  = (u32*)(gcur + 128);             // [NBUCK*CAP] packed entries
    u16* ss    = (u16*)(ebuf + (size_t)NBUCK * CAP); // [NBUCK*CAP + pad] u16

    hipMemsetAsync(gcur, 0, 128 * sizeof(int), stream);
    k1_sc<<<K1B + NCH, 512, 0, stream>>>(z, Wc, bc, Wn, bn, P, Qh, C,
                                         esrc, edst, gcur, ebuf);
    k_bsort<<<NBUCK, 256, 0, stream>>>(gcur, ebuf, bd, ss);
    k2_agg<<<12500, 256, 0, stream>>>(bd, ss, P, Qh, NB);
    k3_out<<<782, 512, 0, stream>>>(C, NB, Wo, bo, out);
}

// Round 14
// 114.389 us; speedup vs baseline: 1.1351x; 1.1351x over previous
//
#include <hip/hip_runtime.h>
#include <math.h>

#define NN 50000
#define NE 800000
#define BSH 7               // bucket = dst >> 7 (128 nodes/bucket)
#define NBUCK 391           // ceil(50000/128)
#define CAP 4096            // per-bucket capacity (mean ~2046, max ~2400)
#define CHUNK 4096          // edges per bscatter chunk
#define NCH ((NE + CHUNK - 1) / CHUNK)   // 196
#define K1B 782             // k1 blocks in merged kernel
#define EPT2 8              // edges per thread in merged bscatter (CHUNK/512)
#define GSZ 24              // gathers per node per round (~98% single-round)

typedef float4 f4;
typedef float2 f2;
typedef unsigned short u16;
typedef unsigned int u32;

__device__ __forceinline__ float sigf(float x) {
    return __builtin_amdgcn_rcpf(1.0f + __expf(-x));
}

__device__ __forceinline__ u16 f32_to_bf16_rne(float f) {
    unsigned u = __float_as_uint(f);
    u += 0x7FFFu + ((u >> 16) & 1u);
    return (u16)(u >> 16);
}

// ---------------- Merged K1 + bscatter (independent work, one launch) -------
#define K1_WFLOATS (3 * 32 * 64 * 2)           // 12288 floats = 48KB
__global__ __launch_bounds__(512, 4) void k1_sc(
    const float* __restrict__ z,
    const float* __restrict__ Wc, const float* __restrict__ bc,
    const float* __restrict__ Wn, const float* __restrict__ bn,
    float* __restrict__ P, u16* __restrict__ Qh, float* __restrict__ C,
    const int* __restrict__ esrc, const int* __restrict__ edst,
    int* __restrict__ gcur, u32* __restrict__ ebuf)
{
    const int tid = threadIdx.x;
    if (blockIdx.x < K1B) {
        __shared__ float sh[K1_WFLOATS + 8 * 256];  // 48KB weights + 8KB tiles
        f2* w2 = (f2*)sh;
        for (int j = tid; j < 3 * 32 * 64; j += 512) {
            const int m = j >> 11, r = j & 2047;
            const int k2 = r >> 6, h = r & 63;
            const float* s = (m == 0) ? (Wc + h * 64 + 2 * k2)
                                      : (Wn + h * 128 + (m - 1) * 64 + 2 * k2);
            w2[(m * 32 + k2) * 64 + h] = *(const f2*)s;
        }
        __syncthreads();

        const int lane = tid & 63;
        const int wid  = tid >> 6;
        f4* tile = (f4*)(sh + K1_WFLOATS) + wid * 64;
        const f2* wl0 = w2;
        const f2* wl1 = w2 + 32 * 64;
        const f2* wl2 = w2 + 2 * 32 * 64;
        const float bcur = bc[lane], bnbr = bn[lane];

        const int gw = blockIdx.x * 8 + wid;
        const int nw = K1B * 8;
        for (int chunk = gw; chunk < NN / 4; chunk += nw) {
            const int n0 = chunk * 4;
            tile[lane] = *(const f4*)(z + n0 * 64 + lane * 4);
            float a0[4], a1[4], a2[4];
            #pragma unroll
            for (int ni = 0; ni < 4; ++ni) { a0[ni] = 0.f; a1[ni] = 0.f; a2[ni] = 0.f; }
            #pragma unroll 2
            for (int k4 = 0; k4 < 16; ++k4) {
                const f2 w0a = wl0[(2 * k4) * 64 + lane], w0b = wl0[(2 * k4 + 1) * 64 + lane];
                const f2 w1a = wl1[(2 * k4) * 64 + lane], w1b = wl1[(2 * k4 + 1) * 64 + lane];
                const f2 w2a = wl2[(2 * k4) * 64 + lane], w2b = wl2[(2 * k4 + 1) * 64 + lane];
                #pragma unroll
                for (int ni = 0; ni < 4; ++ni) {
                    const f4 zz = tile[ni * 16 + k4];  // uniform addr -> LDS broadcast
                    a0[ni] = fmaf(w0b.y, zz.w, fmaf(w0b.x, zz.z, fmaf(w0a.y, zz.y, fmaf(w0a.x, zz.x, a0[ni]))));
                    a1[ni] = fmaf(w1b.y, zz.w, fmaf(w1b.x, zz.z, fmaf(w1a.y, zz.y, fmaf(w1a.x, zz.x, a1[ni]))));
                    a2[ni] = fmaf(w2b.y, zz.w, fmaf(w2b.x, zz.z, fmaf(w2a.y, zz.y, fmaf(w2a.x, zz.x, a2[ni]))));
                }
            }
            #pragma unroll
            for (int ni = 0; ni < 4; ++ni) {
                const int n = n0 + ni;
                C[n * 64 + lane]  = sigf(a0[ni] + bcur);
                P[n * 64 + lane]  = a1[ni] + bnbr;
                Qh[n * 64 + lane] = f32_to_bf16_rne(a2[ni]);
            }
        }
    } else {
        __shared__ int cnt[NBUCK];
        __shared__ int gbase[NBUCK];
        __shared__ int lcur[NBUCK];
        for (int i = tid; i < NBUCK; i += 512) cnt[i] = 0;
        __syncthreads();

        const int base = (blockIdx.x - K1B) * CHUNK;
        u32 ent[EPT2];
        int nb[EPT2];
        #pragma unroll
        for (int t = 0; t < EPT2; ++t) {
            const int e = base + t * 512 + tid;
            if (e < NE) {
                const int d = edst[e], s = esrc[e];
                const int b = d >> BSH;
                ent[t] = ((u32)(d & 127) << 16) | (u32)s;
                nb[t] = b;
                atomicAdd(&cnt[b], 1);
            } else {
                nb[t] = -1;
            }
        }
        __syncthreads();
        for (int i = tid; i < NBUCK; i += 512) {
            gbase[i] = cnt[i] ? atomicAdd(&gcur[i], cnt[i]) : 0;
            lcur[i] = 0;
        }
        __syncthreads();
        #pragma unroll
        for (int t = 0; t < EPT2; ++t) {
            if (nb[t] >= 0) {
                const int li = atomicAdd(&lcur[nb[t]], 1);
                ebuf[nb[t] * CAP + gbase[nb[t]] + li] = ent[t];
            }
        }
    }
}

// One block per 128-node bucket. Node segments rounded to 8 entries (16B),
// pads zero-filled (gather node 0, contribution predicated off).
__global__ __launch_bounds__(256) void k_bsort(const int* __restrict__ gcur,
                                               const u32* __restrict__ ebuf,
                                               u32* __restrict__ bd,
                                               u16* __restrict__ ss)
{
    __shared__ int hist[128];
    __shared__ int lcur[128];
    __shared__ int ps[128];
    __shared__ int tot;
    const int b = blockIdx.x;
    const int ecnt = gcur[b];
    const int e0 = b * CAP;
    const int n0 = b << BSH;
    const int t = threadIdx.x;

    if (t < 128) hist[t] = 0;
    __syncthreads();
    for (int j = t; j < ecnt; j += 256)
        atomicAdd(&hist[(ebuf[e0 + j] >> 16) & 127], 1);
    __syncthreads();
    if (t < 128) ps[t] = (hist[t] + 7) & ~7;     // rounded slot size
    __syncthreads();
    for (int o = 1; o < 128; o <<= 1) {
        int v = 0;
        if (t < 128 && t >= o) v = ps[t - o];
        __syncthreads();
        if (t < 128 && t >= o) ps[t] += v;
        __syncthreads();
    }
    if (t < 128) {
        const int a = hist[t];
        const int r = (a + 7) & ~7;
        const int excl = ps[t] - r;              // exclusive rounded offset
        lcur[t] = excl;
        const int n = n0 + t;
        if (n < NN) bd[n] = ((u32)(e0 + excl) << 8) | (u32)a;
        if (t == 127) tot = ps[127];
    }
    __syncthreads();
    const int zw = (tot + 32) >> 1;              // zero rounded region + guard
    u32* ssw = (u32*)(ss + e0);
    for (int j = t; j < zw; j += 256) ssw[j] = 0;
    __syncthreads();
    for (int j = t; j < ecnt; j += 256) {
        const u32 ent = ebuf[e0 + j];
        const int p = atomicAdd(&lcur[(ent >> 16) & 127], 1);
        ss[e0 + p] = (u16)(ent & 0xFFFFu);
    }
}

// ---------------- K2: one wave per dst node, 24-deep forced gather MLP ------
// 3 aligned dwordx4 loads fetch 24 u16 indices (one wait), then 24 asm
// global_load_ushort issue back-to-back, one vmcnt(0) + sched_barrier(0).
// ~98% of nodes finish in one round.
__global__ __launch_bounds__(256) void k2_agg(
    const u32* __restrict__ bd, const u16* __restrict__ ss,
    const float* __restrict__ P, const u16* __restrict__ Qh,
    float* __restrict__ NB)
{
    const int lane = threadIdx.x & 63;
    const int n = blockIdx.x * 4 + (threadIdx.x >> 6);
    if (n >= NN) return;
    const u32 w = bd[n];
    const int beg = __builtin_amdgcn_readfirstlane((int)(w >> 8));
    const int dg  = __builtin_amdgcn_readfirstlane((int)(w & 255u));
    const u16* qbl = Qh + lane;
    const float p = P[n * 64 + lane];
    float acc = 0.f;

    for (int jb = 0; jb < dg; jb += GSZ) {
        const u16* ip = ss + beg + jb;
        uint4 iv0, iv1, iv2;
        asm volatile("global_load_dwordx4 %0, %1, off" : "=v"(iv0) : "v"(ip));
        asm volatile("global_load_dwordx4 %0, %1, off offset:16" : "=v"(iv1) : "v"(ip));
        asm volatile("global_load_dwordx4 %0, %1, off offset:32" : "=v"(iv2) : "v"(ip));
        asm volatile("s_waitcnt vmcnt(0)" ::: "memory");
        __builtin_amdgcn_sched_barrier(0);
        const u32 wv[12] = {iv0.x, iv0.y, iv0.z, iv0.w,
                            iv1.x, iv1.y, iv1.z, iv1.w,
                            iv2.x, iv2.y, iv2.z, iv2.w};
        u32 q[GSZ];
        #pragma unroll
        for (int t8 = 0; t8 < 12; ++t8) {
            const u16* aL = qbl + ((wv[t8] & 0xFFFFu) << 6);
            const u16* aH = qbl + ((wv[t8] >> 16) << 6);
            asm volatile("global_load_ushort %0, %1, off" : "=v"(q[2 * t8])     : "v"(aL));
            asm volatile("global_load_ushort %0, %1, off" : "=v"(q[2 * t8 + 1]) : "v"(aH));
        }
        asm volatile("s_waitcnt vmcnt(0)" ::: "memory");
        __builtin_amdgcn_sched_barrier(0);
        #pragma unroll
        for (int t = 0; t < GSZ; ++t) {
            const float m = sigf(p + __uint_as_float(q[t] << 16));
            acc += (jb + t < dg) ? m : 0.f;
        }
    }
    NB[n * 64 + lane] = acc;
}

// ---------------- K3: out = tanh([C|NB] @ Wo^T + bo) -----------------------
#define K3_WFLOATS (64 * 64 * 2)               // 8192 floats = 32KB
__global__ __launch_bounds__(512, 4) void k3_out(
    const float* __restrict__ C, const float* __restrict__ NB,
    const float* __restrict__ Wo, const float* __restrict__ bo,
    float* __restrict__ out)
{
    __shared__ float sh[K3_WFLOATS + 8 * 512];
    const int tid = threadIdx.x;
    f2* w2 = (f2*)sh;
    for (int j = tid; j < 64 * 64; j += 512) {
        const int k2 = j >> 6, d = j & 63;
        w2[k2 * 64 + d] = *(const f2*)(Wo + d * 128 + 2 * k2);
    }
    __syncthreads();

    const int lane = tid & 63;
    const int wid  = tid >> 6;
    f4* tile = (f4*)(sh + K3_WFLOATS) + wid * 128;
    const float bout = bo[lane];

    const int gw = blockIdx.x * 8 + wid;
    const int nw = gridDim.x * 8;
    for (int chunk = gw; chunk < NN / 4; chunk += nw) {
        const int n0 = chunk * 4;
        #pragma unroll
        for (int tt = 0; tt < 2; ++tt) {
            const int j = lane + tt * 64;
            const int ni = j >> 5, q = j & 31;
            const float* src = (q < 16) ? (C + (n0 + ni) * 64 + q * 4)
                                        : (NB + (n0 + ni) * 64 + (q - 16) * 4);
            tile[ni * 32 + q] = *(const f4*)src;
        }
        float acc[4];
        #pragma unroll
        for (int ni = 0; ni < 4; ++ni) acc[ni] = 0.f;
        #pragma unroll 2
        for (int k4 = 0; k4 < 32; ++k4) {
            const f2 wa = w2[(2 * k4) * 64 + lane];
            const f2 wb = w2[(2 * k4 + 1) * 64 + lane];
            #pragma unroll
            for (int ni = 0; ni < 4; ++ni) {
                const f4 hv = tile[ni * 32 + k4];
                acc[ni] = fmaf(wb.y, hv.w, fmaf(wb.x, hv.z, fmaf(wa.y, hv.y, fmaf(wa.x, hv.x, acc[ni]))));
            }
        }
        #pragma unroll
        for (int ni = 0; ni < 4; ++ni)
            out[(n0 + ni) * 64 + lane] = tanhf(acc[ni] + bout);
    }
}

extern "C" void kernel_launch(void* const* d_in, const int* in_sizes, int n_in,
                              void* d_out, int out_size, void* d_ws, size_t ws_size,
                              hipStream_t stream) {
    const float* z  = (const float*)d_in[0];
    const int* esrc = (const int*)d_in[1];
    const int* edst = (const int*)d_in[2];
    const float* Wc = (const float*)d_in[3];
    const float* bc = (const float*)d_in[4];
    const float* Wn = (const float*)d_in[5];
    const float* bn = (const float*)d_in[6];
    const float* Wo = (const float*)d_in[7];
    const float* bo = (const float*)d_in[8];
    float* out = (float*)d_out;

    float* P   = (float*)d_ws;                   // [NN*64] f32
    float* C   = P + (size_t)NN * 64;            // [NN*64] f32
    float* NB  = C + (size_t)NN * 64;            // [NN*64] f32
    u16* Qh    = (u16*)(NB + (size_t)NN * 64);   // [NN*64] bf16
    u32* bd    = (u32*)(Qh + (size_t)NN * 64);   // [NN] packed (beg<<8)|deg
    int* gcur  = (int*)(bd + NN + 64);           // [512]
    u32* ebuf  = (u32*)(gcur + 512);             // [NBUCK*CAP] packed entries
    u16* ss    = (u16*)(ebuf + (size_t)NBUCK * CAP); // [NBUCK*CAP + pad] u16

    hipMemsetAsync(gcur, 0, 512 * sizeof(int), stream);
    k1_sc<<<K1B + NCH, 512, 0, stream>>>(z, Wc, bc, Wn, bn, P, Qh, C,
                                         esrc, edst, gcur, ebuf);
    k_bsort<<<NBUCK, 256, 0, stream>>>(gcur, ebuf, bd, ss);
    k2_agg<<<12500, 256, 0, stream>>>(bd, ss, P, Qh, NB);
    k3_out<<<782, 512, 0, stream>>>(C, NB, Wo, bo, out);
}

// Round 15
// 111.529 us; speedup vs baseline: 1.1642x; 1.0256x over previous
//
#include <hip/hip_runtime.h>
#include <math.h>

#define NN 50000
#define NE 800000
#define BSH 7               // bucket = dst >> 7 (128 nodes/bucket)
#define NBUCK 391           // ceil(50000/128)
#define CAP 4096            // per-bucket capacity (mean ~2046, max ~2400)
#define CHUNK 4096          // edges per bscatter chunk
#define NCH ((NE + CHUNK - 1) / CHUNK)   // 196
#define K1B 782             // k1 blocks in merged kernel
#define EPT2 8              // edges per thread in merged bscatter (CHUNK/512)
#define GSZ 24              // gathers per node per round (~98% single-round)

typedef float4 f4;
typedef float2 f2;
typedef unsigned short u16;
typedef unsigned int u32;

__device__ __forceinline__ float sigf(float x) {
    return __builtin_amdgcn_rcpf(1.0f + __expf(-x));
}

__device__ __forceinline__ u16 f32_to_bf16_rne(float f) {
    unsigned u = __float_as_uint(f);
    u += 0x7FFFu + ((u >> 16) & 1u);
    return (u16)(u >> 16);
}

// ---------------- Merged K1 + bscatter (independent work, one launch) -------
#define K1_WFLOATS (3 * 32 * 64 * 2)           // 12288 floats = 48KB
__global__ __launch_bounds__(512, 4) void k1_sc(
    const float* __restrict__ z,
    const float* __restrict__ Wc, const float* __restrict__ bc,
    const float* __restrict__ Wn, const float* __restrict__ bn,
    float* __restrict__ P, u16* __restrict__ Qh, float* __restrict__ C,
    const int* __restrict__ esrc, const int* __restrict__ edst,
    int* __restrict__ gcur, u32* __restrict__ ebuf)
{
    const int tid = threadIdx.x;
    if (blockIdx.x < K1B) {
        __shared__ float sh[K1_WFLOATS + 8 * 256];  // 48KB weights + 8KB tiles
        f2* w2 = (f2*)sh;
        for (int j = tid; j < 3 * 32 * 64; j += 512) {
            const int m = j >> 11, r = j & 2047;
            const int k2 = r >> 6, h = r & 63;
            const float* s = (m == 0) ? (Wc + h * 64 + 2 * k2)
                                      : (Wn + h * 128 + (m - 1) * 64 + 2 * k2);
            w2[(m * 32 + k2) * 64 + h] = *(const f2*)s;
        }
        __syncthreads();

        const int lane = tid & 63;
        const int wid  = tid >> 6;
        f4* tile = (f4*)(sh + K1_WFLOATS) + wid * 64;
        const f2* wl0 = w2;
        const f2* wl1 = w2 + 32 * 64;
        const f2* wl2 = w2 + 2 * 32 * 64;
        const float bcur = bc[lane], bnbr = bn[lane];

        const int gw = blockIdx.x * 8 + wid;
        const int nw = K1B * 8;
        for (int chunk = gw; chunk < NN / 4; chunk += nw) {
            const int n0 = chunk * 4;
            tile[lane] = *(const f4*)(z + n0 * 64 + lane * 4);
            float a0[4], a1[4], a2[4];
            #pragma unroll
            for (int ni = 0; ni < 4; ++ni) { a0[ni] = 0.f; a1[ni] = 0.f; a2[ni] = 0.f; }
            #pragma unroll 2
            for (int k4 = 0; k4 < 16; ++k4) {
                const f2 w0a = wl0[(2 * k4) * 64 + lane], w0b = wl0[(2 * k4 + 1) * 64 + lane];
                const f2 w1a = wl1[(2 * k4) * 64 + lane], w1b = wl1[(2 * k4 + 1) * 64 + lane];
                const f2 w2a = wl2[(2 * k4) * 64 + lane], w2b = wl2[(2 * k4 + 1) * 64 + lane];
                #pragma unroll
                for (int ni = 0; ni < 4; ++ni) {
                    const f4 zz = tile[ni * 16 + k4];  // uniform addr -> LDS broadcast
                    a0[ni] = fmaf(w0b.y, zz.w, fmaf(w0b.x, zz.z, fmaf(w0a.y, zz.y, fmaf(w0a.x, zz.x, a0[ni]))));
                    a1[ni] = fmaf(w1b.y, zz.w, fmaf(w1b.x, zz.z, fmaf(w1a.y, zz.y, fmaf(w1a.x, zz.x, a1[ni]))));
                    a2[ni] = fmaf(w2b.y, zz.w, fmaf(w2b.x, zz.z, fmaf(w2a.y, zz.y, fmaf(w2a.x, zz.x, a2[ni]))));
                }
            }
            #pragma unroll
            for (int ni = 0; ni < 4; ++ni) {
                const int n = n0 + ni;
                C[n * 64 + lane]  = sigf(a0[ni] + bcur);
                P[n * 64 + lane]  = a1[ni] + bnbr;
                Qh[n * 64 + lane] = f32_to_bf16_rne(a2[ni]);
            }
        }
    } else {
        __shared__ int cnt[NBUCK];
        __shared__ int gbase[NBUCK];
        __shared__ int lcur[NBUCK];
        for (int i = tid; i < NBUCK; i += 512) cnt[i] = 0;
        __syncthreads();

        const int base = (blockIdx.x - K1B) * CHUNK;
        u32 ent[EPT2];
        int nb[EPT2];
        #pragma unroll
        for (int t = 0; t < EPT2; ++t) {
            const int e = base + t * 512 + tid;
            if (e < NE) {
                const int d = edst[e], s = esrc[e];
                const int b = d >> BSH;
                ent[t] = ((u32)(d & 127) << 16) | (u32)s;
                nb[t] = b;
                atomicAdd(&cnt[b], 1);
            } else {
                nb[t] = -1;
            }
        }
        __syncthreads();
        for (int i = tid; i < NBUCK; i += 512) {
            gbase[i] = cnt[i] ? atomicAdd(&gcur[i], cnt[i]) : 0;
            lcur[i] = 0;
        }
        __syncthreads();
        #pragma unroll
        for (int t = 0; t < EPT2; ++t) {
            if (nb[t] >= 0) {
                const int li = atomicAdd(&lcur[nb[t]], 1);
                ebuf[nb[t] * CAP + gbase[nb[t]] + li] = ent[t];
            }
        }
    }
}

// One block per 128-node bucket. Node segments rounded to 8 entries (16B),
// pads zero-filled (gather node 0, contribution predicated off).
__global__ __launch_bounds__(256) void k_bsort(const int* __restrict__ gcur,
                                               const u32* __restrict__ ebuf,
                                               u32* __restrict__ bd,
                                               u16* __restrict__ ss)
{
    __shared__ int hist[128];
    __shared__ int lcur[128];
    __shared__ int ps[128];
    __shared__ int tot;
    const int b = blockIdx.x;
    const int ecnt = gcur[b];
    const int e0 = b * CAP;
    const int n0 = b << BSH;
    const int t = threadIdx.x;

    if (t < 128) hist[t] = 0;
    __syncthreads();
    for (int j = t; j < ecnt; j += 256)
        atomicAdd(&hist[(ebuf[e0 + j] >> 16) & 127], 1);
    __syncthreads();
    if (t < 128) ps[t] = (hist[t] + 7) & ~7;     // rounded slot size
    __syncthreads();
    for (int o = 1; o < 128; o <<= 1) {
        int v = 0;
        if (t < 128 && t >= o) v = ps[t - o];
        __syncthreads();
        if (t < 128 && t >= o) ps[t] += v;
        __syncthreads();
    }
    if (t < 128) {
        const int a = hist[t];
        const int r = (a + 7) & ~7;
        const int excl = ps[t] - r;              // exclusive rounded offset
        lcur[t] = excl;
        const int n = n0 + t;
        if (n < NN) bd[n] = ((u32)(e0 + excl) << 8) | (u32)a;
        if (t == 127) tot = ps[127];
    }
    __syncthreads();
    const int zw = (tot + 48) >> 1;              // zero region + GSZ over-read guard
    u32* ssw = (u32*)(ss + e0);
    for (int j = t; j < zw; j += 256) ssw[j] = 0;
    __syncthreads();
    for (int j = t; j < ecnt; j += 256) {
        const u32 ent = ebuf[e0 + j];
        const int p = atomicAdd(&lcur[(ent >> 16) & 127], 1);
        ss[e0 + p] = (u16)(ent & 0xFFFFu);
    }
}

// ---------------- Fused K2+K3: one wave per 4 dst nodes ---------------------
// Per node: R14-proven gather structure (3 aligned idx dwordx4 -> 24 asm
// ushort gathers -> one vmcnt(0)+sched_barrier). acc rows staged to the
// wave-private LDS tile; then ONE 4-node-amortized Wo contraction. NB never
// touches global memory.
#define KF_WFLOATS (64 * 64 * 2)               // Wo: 8192 floats = 32KB
__global__ __launch_bounds__(512) void k23(
    const u32* __restrict__ bd, const u16* __restrict__ ss,
    const float* __restrict__ P, const u16* __restrict__ Qh,
    const float* __restrict__ C, const float* __restrict__ Wo,
    const float* __restrict__ bo, float* __restrict__ out)
{
    __shared__ float sh[KF_WFLOATS + 8 * 512];  // 32KB Wo + 16KB tiles = 48KB
    const int tid = threadIdx.x;
    f2* w2 = (f2*)sh;
    for (int j = tid; j < 64 * 64; j += 512) {
        const int k2 = j >> 6, d = j & 63;
        w2[k2 * 64 + d] = *(const f2*)(Wo + d * 128 + 2 * k2);
    }
    __syncthreads();

    const int lane = tid & 63;
    const int wid  = tid >> 6;
    float* tile = sh + KF_WFLOATS + wid * 512;  // [4 nodes][C row | NB row]
    const f4* t4 = (const f4*)tile;
    const u16* qbl = Qh + lane;
    const float bout = bo[lane];

    for (int chunk = blockIdx.x * 8 + wid; chunk < NN / 4; chunk += gridDim.x * 8) {
        const int n0 = chunk * 4;
        #pragma unroll
        for (int i = 0; i < 4; ++i) {
            const int n = n0 + i;
            const u32 w = bd[n];
            const int beg = __builtin_amdgcn_readfirstlane((int)(w >> 8));
            const int dg  = __builtin_amdgcn_readfirstlane((int)(w & 255u));
            const float p = P[n * 64 + lane];
            tile[i * 128 + lane] = C[n * 64 + lane];
            float acc = 0.f;

            int jb = 0;
            for (; jb + GSZ <= dg; jb += GSZ) {  // full rounds: no predication
                const u16* ip = ss + beg + jb;
                uint4 iv0, iv1, iv2;
                asm volatile("global_load_dwordx4 %0, %1, off" : "=v"(iv0) : "v"(ip));
                asm volatile("global_load_dwordx4 %0, %1, off offset:16" : "=v"(iv1) : "v"(ip));
                asm volatile("global_load_dwordx4 %0, %1, off offset:32" : "=v"(iv2) : "v"(ip));
                asm volatile("s_waitcnt vmcnt(0)" ::: "memory");
                __builtin_amdgcn_sched_barrier(0);
                const u32 wv[12] = {iv0.x, iv0.y, iv0.z, iv0.w,
                                    iv1.x, iv1.y, iv1.z, iv1.w,
                                    iv2.x, iv2.y, iv2.z, iv2.w};
                u32 q[GSZ];
                #pragma unroll
                for (int t8 = 0; t8 < 12; ++t8) {
                    const u16* aL = qbl + ((wv[t8] & 0xFFFFu) << 6);
                    const u16* aH = qbl + ((wv[t8] >> 16) << 6);
                    asm volatile("global_load_ushort %0, %1, off" : "=v"(q[2 * t8])     : "v"(aL));
                    asm volatile("global_load_ushort %0, %1, off" : "=v"(q[2 * t8 + 1]) : "v"(aH));
                }
                asm volatile("s_waitcnt vmcnt(0)" ::: "memory");
                __builtin_amdgcn_sched_barrier(0);
                #pragma unroll
                for (int t = 0; t < GSZ; ++t)
                    acc += sigf(p + __uint_as_float(q[t] << 16));
            }
            if (jb < dg) {                       // predicated tail round
                const u16* ip = ss + beg + jb;
                uint4 iv0, iv1, iv2;
                asm volatile("global_load_dwordx4 %0, %1, off" : "=v"(iv0) : "v"(ip));
                asm volatile("global_load_dwordx4 %0, %1, off offset:16" : "=v"(iv1) : "v"(ip));
                asm volatile("global_load_dwordx4 %0, %1, off offset:32" : "=v"(iv2) : "v"(ip));
                asm volatile("s_waitcnt vmcnt(0)" ::: "memory");
                __builtin_amdgcn_sched_barrier(0);
                const u32 wv[12] = {iv0.x, iv0.y, iv0.z, iv0.w,
                                    iv1.x, iv1.y, iv1.z, iv1.w,
                                    iv2.x, iv2.y, iv2.z, iv2.w};
                u32 q[GSZ];
                #pragma unroll
                for (int t8 = 0; t8 < 12; ++t8) {
                    const u16* aL = qbl + ((wv[t8] & 0xFFFFu) << 6);
                    const u16* aH = qbl + ((wv[t8] >> 16) << 6);
                    asm volatile("global_load_ushort %0, %1, off" : "=v"(q[2 * t8])     : "v"(aL));
                    asm volatile("global_load_ushort %0, %1, off" : "=v"(q[2 * t8 + 1]) : "v"(aH));
                }
                asm volatile("s_waitcnt vmcnt(0)" ::: "memory");
                __builtin_amdgcn_sched_barrier(0);
                #pragma unroll
                for (int t = 0; t < GSZ; ++t) {
                    const float m = sigf(p + __uint_as_float(q[t] << 16));
                    acc += (jb + t < dg) ? m : 0.f;
                }
            }
            tile[i * 128 + 64 + lane] = acc;     // wave-internal: no barrier
        }

        float a2[4] = {0.f, 0.f, 0.f, 0.f};
        #pragma unroll 2
        for (int k4 = 0; k4 < 32; ++k4) {
            const f2 wa = w2[(2 * k4) * 64 + lane];
            const f2 wb = w2[(2 * k4 + 1) * 64 + lane];
            #pragma unroll
            for (int i = 0; i < 4; ++i) {
                const f4 hv = t4[i * 32 + k4];   // uniform addr -> LDS broadcast
                a2[i] = fmaf(wb.y, hv.w, fmaf(wb.x, hv.z, fmaf(wa.y, hv.y, fmaf(wa.x, hv.x, a2[i]))));
            }
        }
        #pragma unroll
        for (int i = 0; i < 4; ++i)
            out[(n0 + i) * 64 + lane] = tanhf(a2[i] + bout);
    }
}

extern "C" void kernel_launch(void* const* d_in, const int* in_sizes, int n_in,
                              void* d_out, int out_size, void* d_ws, size_t ws_size,
                              hipStream_t stream) {
    const float* z  = (const float*)d_in[0];
    const int* esrc = (const int*)d_in[1];
    const int* edst = (const int*)d_in[2];
    const float* Wc = (const float*)d_in[3];
    const float* bc = (const float*)d_in[4];
    const float* Wn = (const float*)d_in[5];
    const float* bn = (const float*)d_in[6];
    const float* Wo = (const float*)d_in[7];
    const float* bo = (const float*)d_in[8];
    float* out = (float*)d_out;

    float* P   = (float*)d_ws;                   // [NN*64] f32
    float* C   = P + (size_t)NN * 64;            // [NN*64] f32
    u16* Qh    = (u16*)(C + (size_t)NN * 64);    // [NN*64] bf16
    u32* bd    = (u32*)(Qh + (size_t)NN * 64);   // [NN] packed (beg<<8)|deg
    int* gcur  = (int*)(bd + NN + 64);           // [512]
    u32* ebuf  = (u32*)(gcur + 512);             // [NBUCK*CAP] packed entries
    u16* ss    = (u16*)(ebuf + (size_t)NBUCK * CAP); // [NBUCK*CAP + pad] u16

    hipMemsetAsync(gcur, 0, 512 * sizeof(int), stream);
    k1_sc<<<K1B + NCH, 512, 0, stream>>>(z, Wc, bc, Wn, bn, P, Qh, C,
                                         esrc, edst, gcur, ebuf);
    k_bsort<<<NBUCK, 256, 0, stream>>>(gcur, ebuf, bd, ss);
    k23<<<1563, 512, 0, stream>>>(bd, ss, P, Qh, C, Wo, bo, out);
}

// Round 17
// 106.613 us; speedup vs baseline: 1.2179x; 1.0461x over previous
//
#include <hip/hip_runtime.h>
#include <math.h>

#define NN 50000
#define NE 800000
#define BSH 7               // bucket = dst >> 7 (128 nodes/bucket)
#define NBUCK 391           // ceil(50000/128)
#define CAP 4096            // per-bucket capacity (mean ~2046, max ~2400)
#define CHUNK 4096          // edges per bscatter chunk
#define NCH ((NE + CHUNK - 1) / CHUNK)   // 196
#define K1B 782             // k1 blocks in merged kernel
#define EPT2 8              // edges per thread in merged bscatter (CHUNK/512)
#define SENT 50000          // sentinel node index: Qh[SENT][*] = -inf (sigf -> 0)

typedef float4 f4;
typedef float2 f2;
typedef unsigned short u16;
typedef unsigned int u32;

__device__ __forceinline__ float sigf(float x) {
    return __builtin_amdgcn_rcpf(1.0f + __expf(-x));
}

__device__ __forceinline__ u16 f32_to_bf16_rne(float f) {
    unsigned u = __float_as_uint(f);
    u += 0x7FFFu + ((u >> 16) & 1u);
    return (u16)(u >> 16);
}

// ---------------- Merged K1 + bscatter (independent work, one launch) -------
#define K1_WFLOATS (3 * 32 * 64 * 2)           // 12288 floats = 48KB
__global__ __launch_bounds__(512, 4) void k1_sc(
    const float* __restrict__ z,
    const float* __restrict__ Wc, const float* __restrict__ bc,
    const float* __restrict__ Wn, const float* __restrict__ bn,
    float* __restrict__ P, u16* __restrict__ Qh, float* __restrict__ C,
    const int* __restrict__ esrc, const int* __restrict__ edst,
    int* __restrict__ gcur, u32* __restrict__ ebuf)
{
    const int tid = threadIdx.x;
    if (blockIdx.x < K1B) {
        __shared__ float sh[K1_WFLOATS + 8 * 256];  // 48KB weights + 8KB tiles
        f2* w2 = (f2*)sh;
        for (int j = tid; j < 3 * 32 * 64; j += 512) {
            const int m = j >> 11, r = j & 2047;
            const int k2 = r >> 6, h = r & 63;
            const float* s = (m == 0) ? (Wc + h * 64 + 2 * k2)
                                      : (Wn + h * 128 + (m - 1) * 64 + 2 * k2);
            w2[(m * 32 + k2) * 64 + h] = *(const f2*)s;
        }
        __syncthreads();

        const int lane = tid & 63;
        const int wid  = tid >> 6;
        f4* tile = (f4*)(sh + K1_WFLOATS) + wid * 64;
        const f2* wl0 = w2;
        const f2* wl1 = w2 + 32 * 64;
        const f2* wl2 = w2 + 2 * 32 * 64;
        const float bcur = bc[lane], bnbr = bn[lane];

        const int gw = blockIdx.x * 8 + wid;
        const int nw = K1B * 8;
        for (int chunk = gw; chunk < NN / 4; chunk += nw) {
            const int n0 = chunk * 4;
            tile[lane] = *(const f4*)(z + n0 * 64 + lane * 4);
            float a0[4], a1[4], a2[4];
            #pragma unroll
            for (int ni = 0; ni < 4; ++ni) { a0[ni] = 0.f; a1[ni] = 0.f; a2[ni] = 0.f; }
            #pragma unroll 2
            for (int k4 = 0; k4 < 16; ++k4) {
                const f2 w0a = wl0[(2 * k4) * 64 + lane], w0b = wl0[(2 * k4 + 1) * 64 + lane];
                const f2 w1a = wl1[(2 * k4) * 64 + lane], w1b = wl1[(2 * k4 + 1) * 64 + lane];
                const f2 w2a = wl2[(2 * k4) * 64 + lane], w2b = wl2[(2 * k4 + 1) * 64 + lane];
                #pragma unroll
                for (int ni = 0; ni < 4; ++ni) {
                    const f4 zz = tile[ni * 16 + k4];  // uniform addr -> LDS broadcast
                    a0[ni] = fmaf(w0b.y, zz.w, fmaf(w0b.x, zz.z, fmaf(w0a.y, zz.y, fmaf(w0a.x, zz.x, a0[ni]))));
                    a1[ni] = fmaf(w1b.y, zz.w, fmaf(w1b.x, zz.z, fmaf(w1a.y, zz.y, fmaf(w1a.x, zz.x, a1[ni]))));
                    a2[ni] = fmaf(w2b.y, zz.w, fmaf(w2b.x, zz.z, fmaf(w2a.y, zz.y, fmaf(w2a.x, zz.x, a2[ni]))));
                }
            }
            #pragma unroll
            for (int ni = 0; ni < 4; ++ni) {
                const int n = n0 + ni;
                C[n * 64 + lane]  = sigf(a0[ni] + bcur);
                P[n * 64 + lane]  = a1[ni] + bnbr;
                Qh[n * 64 + lane] = f32_to_bf16_rne(a2[ni]);
            }
        }
    } else {
        // first scatter block also writes the sentinel Q row (-inf bf16)
        if (blockIdx.x == K1B && tid < 64) Qh[(size_t)SENT * 64 + tid] = 0xFF80u;

        __shared__ int cnt[NBUCK];
        __shared__ int gbase[NBUCK];
        __shared__ int lcur[NBUCK];
        for (int i = tid; i < NBUCK; i += 512) cnt[i] = 0;
        __syncthreads();

        const int base = (blockIdx.x - K1B) * CHUNK;
        u32 ent[EPT2];
        int nb[EPT2];
        #pragma unroll
        for (int t = 0; t < EPT2; ++t) {
            const int e = base + t * 512 + tid;
            if (e < NE) {
                const int d = edst[e], s = esrc[e];
                const int b = d >> BSH;
                ent[t] = ((u32)(d & 127) << 16) | (u32)s;
                nb[t] = b;
                atomicAdd(&cnt[b], 1);
            } else {
                nb[t] = -1;
            }
        }
        __syncthreads();
        for (int i = tid; i < NBUCK; i += 512) {
            gbase[i] = cnt[i] ? atomicAdd(&gcur[i], cnt[i]) : 0;
            lcur[i] = 0;
        }
        __syncthreads();
        #pragma unroll
        for (int t = 0; t < EPT2; ++t) {
            if (nb[t] >= 0) {
                const int li = atomicAdd(&lcur[nb[t]], 1);
                ebuf[nb[t] * CAP + gbase[nb[t]] + li] = ent[t];
            }
        }
    }
}

// One block per 128-node bucket. Node segments rounded to 8 entries (16B);
// pad slots filled with SENT (gather hits the -inf row -> contributes 0).
__global__ __launch_bounds__(256) void k_bsort(const int* __restrict__ gcur,
                                               const u32* __restrict__ ebuf,
                                               u32* __restrict__ bd,
                                               u16* __restrict__ ss)
{
    __shared__ int hist[128];
    __shared__ int lcur[128];
    __shared__ int ps[128];
    __shared__ int tot;
    const int b = blockIdx.x;
    const int ecnt = gcur[b];
    const int e0 = b * CAP;
    const int n0 = b << BSH;
    const int t = threadIdx.x;

    if (t < 128) hist[t] = 0;
    __syncthreads();
    for (int j = t; j < ecnt; j += 256)
        atomicAdd(&hist[(ebuf[e0 + j] >> 16) & 127], 1);
    __syncthreads();
    if (t < 128) ps[t] = (hist[t] + 7) & ~7;     // rounded slot size
    __syncthreads();
    for (int o = 1; o < 128; o <<= 1) {
        int v = 0;
        if (t < 128 && t >= o) v = ps[t - o];
        __syncthreads();
        if (t < 128 && t >= o) ps[t] += v;
        __syncthreads();
    }
    if (t < 128) {
        const int a = hist[t];
        const int r = (a + 7) & ~7;
        const int excl = ps[t] - r;              // exclusive rounded offset
        lcur[t] = excl;
        const int n = n0 + t;
        if (n < NN) bd[n] = ((u32)(e0 + excl) << 8) | (u32)a;
        if (t == 127) tot = ps[127];
    }
    __syncthreads();
    const int zw = (tot + 48) >> 1;              // sentinel-fill region + guard
    u32* ssw = (u32*)(ss + e0);
    for (int j = t; j < zw; j += 256) ssw[j] = 0xC350C350u;  // 50000|50000
    __syncthreads();
    for (int j = t; j < ecnt; j += 256) {
        const u32 ent = ebuf[e0 + j];
        const int p = atomicAdd(&lcur[(ent >> 16) & 127], 1);
        ss[e0 + p] = (u16)(ent & 0xFFFFu);
    }
}

// One gather round: NQ in {8,16,24}. NQ/8 aligned dwordx4 idx loads (one
// wait), then NQ asm ushort gathers back-to-back (one wait). No predication:
// pad slots hit the sentinel row and contribute exactly 0.
template<int NQ>
__device__ __forceinline__ void round_g(const u16* __restrict__ ip,
                                        const u16* __restrict__ qbl,
                                        float p, float& acc)
{
    uint4 iv0, iv1, iv2;
    asm volatile("global_load_dwordx4 %0, %1, off" : "=v"(iv0) : "v"(ip));
    if constexpr (NQ >= 16)
        asm volatile("global_load_dwordx4 %0, %1, off offset:16" : "=v"(iv1) : "v"(ip));
    if constexpr (NQ >= 24)
        asm volatile("global_load_dwordx4 %0, %1, off offset:32" : "=v"(iv2) : "v"(ip));
    asm volatile("s_waitcnt vmcnt(0)" ::: "memory");
    __builtin_amdgcn_sched_barrier(0);
    u32 wv[NQ / 2];
    wv[0] = iv0.x; wv[1] = iv0.y; wv[2] = iv0.z; wv[3] = iv0.w;
    if constexpr (NQ >= 16) { wv[4] = iv1.x; wv[5] = iv1.y; wv[6] = iv1.z; wv[7] = iv1.w; }
    if constexpr (NQ >= 24) { wv[8] = iv2.x; wv[9] = iv2.y; wv[10] = iv2.z; wv[11] = iv2.w; }
    u32 q[NQ];
    #pragma unroll
    for (int t8 = 0; t8 < NQ / 2; ++t8) {
        const u16* aL = qbl + ((wv[t8] & 0xFFFFu) << 6);
        const u16* aH = qbl + ((wv[t8] >> 16) << 6);
        asm volatile("global_load_ushort %0, %1, off" : "=v"(q[2 * t8])     : "v"(aL));
        asm volatile("global_load_ushort %0, %1, off" : "=v"(q[2 * t8 + 1]) : "v"(aH));
    }
    asm volatile("s_waitcnt vmcnt(0)" ::: "memory");
    __builtin_amdgcn_sched_barrier(0);
    #pragma unroll
    for (int t = 0; t < NQ; ++t)
        acc += sigf(p + __uint_as_float(q[t] << 16));
}

// ---------------- Fused K2+K3: one wave per 4 dst nodes ---------------------
// Mixed-precision Wo in LDS: C-part (|C|<=1) packed bf16 = 8KB; NB-part
// (|NB| up to ~35) f32 = 16KB. + 16KB tiles = 40KB -> 4 blocks/CU (100%
// occupancy cap). Per node: exact-rdg sentinel gather rounds (24/16/8),
// acc to wave-private LDS tile, then ONE 4-node-amortized contraction.
__global__ __launch_bounds__(512, 8) void k23(
    const u32* __restrict__ bd, const u16* __restrict__ ss,
    const float* __restrict__ P, const u16* __restrict__ Qh,
    const float* __restrict__ C, const float* __restrict__ Wo,
    const float* __restrict__ bo, float* __restrict__ out)
{
    __shared__ u32 w1u[32 * 64];                // C-part:  [k2*64+d] bf16x2 (8KB)
    __shared__ f2  w2f[32 * 64];                // NB-part: [k2*64+d] f32x2 (16KB)
    __shared__ float tiles[8 * 512];            // per-wave [4 nodes][C row | NB row]
    const int tid = threadIdx.x;
    for (int j = tid; j < 32 * 64; j += 512) {
        const int k2 = j >> 6, d = j & 63;
        const f2 wc = *(const f2*)(Wo + d * 128 + 2 * k2);
        w1u[k2 * 64 + d] = ((u32)f32_to_bf16_rne(wc.y) << 16) | (u32)f32_to_bf16_rne(wc.x);
        w2f[k2 * 64 + d] = *(const f2*)(Wo + d * 128 + 64 + 2 * k2);
    }
    __syncthreads();

    const int lane = tid & 63;
    const int wid  = tid >> 6;
    float* tile = tiles + wid * 512;
    const f4* t4 = (const f4*)tile;
    const u16* qbl = Qh + lane;
    const float bout = bo[lane];

    for (int chunk = blockIdx.x * 8 + wid; chunk < NN / 4; chunk += gridDim.x * 8) {
        const int n0 = chunk * 4;
        #pragma unroll
        for (int i = 0; i < 4; ++i) {
            const int n = n0 + i;
            const u32 w = bd[n];
            const int beg = __builtin_amdgcn_readfirstlane((int)(w >> 8));
            const int dg  = __builtin_amdgcn_readfirstlane((int)(w & 255u));
            const int rdg = (dg + 7) & ~7;
            const float p = P[n * 64 + lane];
            tile[i * 128 + lane] = C[n * 64 + lane];
            float acc = 0.f;

            int jb = 0;
            for (; jb + 24 <= rdg; jb += 24)
                round_g<24>(ss + beg + jb, qbl, p, acc);
            const int rem = rdg - jb;            // 0, 8, or 16 (wave-uniform)
            if (rem == 16)     round_g<16>(ss + beg + jb, qbl, p, acc);
            else if (rem == 8) round_g<8>(ss + beg + jb, qbl, p, acc);

            tile[i * 128 + 64 + lane] = acc;     // wave-internal: no barrier
        }

        float a2[4] = {0.f, 0.f, 0.f, 0.f};
        // C-part contraction (bf16 weights; |C| <= 1 -> error ~2e-3)
        #pragma unroll 2
        for (int k4 = 0; k4 < 16; ++k4) {
            const u32 ua = w1u[(2 * k4) * 64 + lane];
            const u32 ub = w1u[(2 * k4 + 1) * 64 + lane];
            const float wa0 = __uint_as_float(ua << 16);
            const float wa1 = __uint_as_float(ua & 0xFFFF0000u);
            const float wb0 = __uint_as_float(ub << 16);
            const float wb1 = __uint_as_float(ub & 0xFFFF0000u);
            #pragma unroll
            for (int i = 0; i < 4; ++i) {
                const f4 hv = t4[i * 32 + k4];   // uniform addr -> LDS broadcast
                a2[i] = fmaf(wb1, hv.w, fmaf(wb0, hv.z, fmaf(wa1, hv.y, fmaf(wa0, hv.x, a2[i]))));
            }
        }
        // NB-part contraction (f32 weights; |NB| up to ~35 -> exact)
        #pragma unroll 2
        for (int k4 = 0; k4 < 16; ++k4) {
            const f2 wa = w2f[(2 * k4) * 64 + lane];
            const f2 wb = w2f[(2 * k4 + 1) * 64 + lane];
            #pragma unroll
            for (int i = 0; i < 4; ++i) {
                const f4 hv = t4[i * 32 + 16 + k4];
                a2[i] = fmaf(wb.y, hv.w, fmaf(wb.x, hv.z, fmaf(wa.y, hv.y, fmaf(wa.x, hv.x, a2[i]))));
            }
        }
        #pragma unroll
        for (int i = 0; i < 4; ++i)
            out[(n0 + i) * 64 + lane] = tanhf(a2[i] + bout);
    }
}

extern "C" void kernel_launch(void* const* d_in, const int* in_sizes, int n_in,
                              void* d_out, int out_size, void* d_ws, size_t ws_size,
                              hipStream_t stream) {
    const float* z  = (const float*)d_in[0];
    const int* esrc = (const int*)d_in[1];
    const int* edst = (const int*)d_in[2];
    const float* Wc = (const float*)d_in[3];
    const float* bc = (const float*)d_in[4];
    const float* Wn = (const float*)d_in[5];
    const float* bn = (const float*)d_in[6];
    const float* Wo = (const float*)d_in[7];
    const float* bo = (const float*)d_in[8];
    float* out = (float*)d_out;

    float* P   = (float*)d_ws;                   // [NN*64] f32
    float* C   = P + (size_t)NN * 64;            // [NN*64] f32
    u16* Qh    = (u16*)(C + (size_t)NN * 64);    // [(NN+1)*64] bf16 (+ sentinel row)
    u32* bd    = (u32*)(Qh + (size_t)(NN + 1) * 64); // [NN] packed (beg<<8)|deg
    int* gcur  = (int*)(bd + NN + 64);           // [512]
    u32* ebuf  = (u32*)(gcur + 512);             // [NBUCK*CAP] packed entries
    u16* ss    = (u16*)(ebuf + (size_t)NBUCK * CAP); // [NBUCK*CAP + pad] u16

    hipMemsetAsync(gcur, 0, 512 * sizeof(int), stream);
    k1_sc<<<K1B + NCH, 512, 0, stream>>>(z, Wc, bc, Wn, bn, P, Qh, C,
                                         esrc, edst, gcur, ebuf);
    k_bsort<<<NBUCK, 256, 0, stream>>>(gcur, ebuf, bd, ss);
    k23<<<1563, 512, 0, stream>>>(bd, ss, P, Qh, C, Wo, bo, out);
}